// Round 3
// baseline (151.151 us; speedup 1.0000x reference)
//
#include <hip/hip_runtime.h>
#include <hip/hip_bf16.h>
#include <stdint.h>

#define HD 768

typedef __attribute__((ext_vector_type(8))) short bf16x8;
typedef __attribute__((ext_vector_type(4))) float f32x4;
typedef __attribute__((ext_vector_type(4))) unsigned short u16x4;

typedef __attribute__((address_space(3))) void lds_void_t;
typedef const __attribute__((address_space(1))) void gbl_void_t;

__device__ inline void gload_lds16(const void* g, void* l) {
  __builtin_amdgcn_global_load_lds((gbl_void_t*)g, (lds_void_t*)l, 16, 0, 0);
}

__device__ inline unsigned short f2bf(float f) {
  union { float f; unsigned int u; } v; v.f = f;
  return (unsigned short)((v.u + 0x7fffu + ((v.u >> 16) & 1u)) >> 16);
}
__device__ inline float bf2f(unsigned short u) {
  union { unsigned int uu; float f; } v; v.uu = ((unsigned int)u) << 16;
  return v.f;
}

#define BAR() asm volatile("s_barrier" ::: "memory")
#define LGKM(N) { asm volatile("s_waitcnt lgkmcnt(" #N ")" ::: "memory"); __builtin_amdgcn_sched_barrier(0); }
#define VMC(N) asm volatile("s_waitcnt vmcnt(" #N ")" ::: "memory")

// ---------------- prep + monarch fused ----------------
// bid < 1024: fat blocks, 16 rows each: read x fp32, write xb bf16, compute
//   mixed = P B2 P B1 x for those rows (w1/w2 fragments packed in-register from
//   raw weights, prefetched before the phase-A barrier), write mx bf16.
// bid [1024,3328): Gwb cvt.  bid [3328,3616): Opk pack.
__global__ __launch_bounds__(256, 2)
void prep_monarch_all_kernel(const float* __restrict__ x,
                             const float* __restrict__ gw, const float* __restrict__ ow,
                             const float* __restrict__ w1, const float* __restrict__ w2,
                             unsigned short* __restrict__ xb,
                             unsigned short* __restrict__ Gwb,
                             unsigned short* __restrict__ Opk,
                             unsigned short* __restrict__ mx) {
  __shared__ __align__(16) unsigned char xtile[24576];  // 16 x 768 bf16 (swizzled)
  __shared__ __align__(16) unsigned char zl[24576];     // z / u tile (swizzled)
  int bid = blockIdx.x;
  if (bid < 1024) {
    const int tid = threadIdx.x, lane = tid & 63, wid = tid >> 6;
    const int lr = lane & 15, lg = lane >> 4;
    const size_t m0 = (size_t)bid * 16;

    // ---- weight fragment prefetch (no LDS dependency; overlaps phase A) ----
    // w1 frags for k = wid*4+kb: B[q = nt*16+lr][kk = ks*32+lg*8+j] = w1[k][kk][q], kk<48 else 0
    bf16x8 w1r[4][3][2];
#pragma unroll
    for (int kb = 0; kb < 4; ++kb) {
      const int k = wid * 4 + kb;
#pragma unroll
      for (int nt = 0; nt < 3; ++nt) {
        const int q = nt * 16 + lr;
#pragma unroll
        for (int ks = 0; ks < 2; ++ks) {
          bf16x8 p;
#pragma unroll
          for (int j = 0; j < 8; ++j) {
            int kk = ks * 32 + lg * 8 + j;
            float v = (kk < 48) ? w1[(k * 48 + kk) * 48 + q] : 0.0f;
            p[j] = (short)f2bf(v);
          }
          w1r[kb][nt][ks] = p;
        }
      }
    }
    // w2 frags for q = wid*12+qq: B[k2 = lr][kk = lg*8+j] = w2[q][kk][k2], kk<16 else 0
    bf16x8 w2r[12];
#pragma unroll
    for (int qq = 0; qq < 12; ++qq) {
      const int q = wid * 12 + qq;
      bf16x8 p;
#pragma unroll
      for (int j = 0; j < 8; ++j) {
        int kk = lg * 8 + j;
        float v = (kk < 16) ? w2[(q * 16 + kk) * 16 + lr] : 0.0f;
        p[j] = (short)f2bf(v);
      }
      w2r[qq] = p;
    }

    // ---- phase A: x fp32 -> xb bf16 (coalesced) + xtile LDS (swizzled) ----
    const float4* xsrc = (const float4*)x + (size_t)bid * 3072;
    ushort4* xdst = (ushort4*)xb + (size_t)bid * 3072;
#pragma unroll
    for (int p = 0; p < 12; ++p) {
      int id = p * 256 + tid;             // 3072 float4 chunks
      float4 v = xsrc[id];
      ushort4 o;
      o.x = f2bf(v.x); o.y = f2bf(v.y); o.z = f2bf(v.z); o.w = f2bf(v.w);
      xdst[id] = o;
      int row = id / 192, c4 = id - row * 192;
      uint2 u2;
      u2.x = (unsigned int)o.x | ((unsigned int)o.y << 16);
      u2.y = (unsigned int)o.z | ((unsigned int)o.w << 16);
      *(uint2*)(xtile + ((row * 1536 + c4 * 8) ^ ((row & 7) << 4))) = u2;
    }
    __syncthreads();

    // ---- stage 1: z_k[16x48] = x_k[16x48] @ w1[k] (K padded 48->64) ----
#pragma unroll
    for (int kb = 0; kb < 4; ++kb) {
      const int k = wid * 4 + kb;
      const int abase = lr * 1536 + k * 96;
      const int aswz = (lr & 7) << 4;
      bf16x8 a0 = *(const bf16x8*)(xtile + ((abase + lg * 16) ^ aswz));
      bf16x8 a1 = (bf16x8){0, 0, 0, 0, 0, 0, 0, 0};
      if (lg < 2) a1 = *(const bf16x8*)(xtile + ((abase + 64 + lg * 16) ^ aswz));
#pragma unroll
      for (int nt = 0; nt < 3; ++nt) {
        f32x4 c = {0, 0, 0, 0};
        c = __builtin_amdgcn_mfma_f32_16x16x32_bf16(a0, w1r[kb][nt][0], c, 0, 0, 0);
        c = __builtin_amdgcn_mfma_f32_16x16x32_bf16(a1, w1r[kb][nt][1], c, 0, 0, 0);
        // z[row][q*16+k], q = nt*16+lr_out; C layout: col=lr, row=lg*4+i
#pragma unroll
        for (int i = 0; i < 4; ++i) {
          int row = lg * 4 + i;
          *(unsigned short*)(zl + ((row * 1536 + nt * 512 + lr * 32 + k * 2) ^ ((row & 7) << 4))) = f2bf(c[i]);
        }
      }
    }
    __syncthreads();

    // ---- stage 2: u_q[16x16] = z'_q[16x16] @ w2[q] (K padded 16->32) ----
    unsigned int upk[4][6];
#pragma unroll
    for (int qq = 0; qq < 12; ++qq) {
      const int q = wid * 12 + qq;
      bf16x8 a = (bf16x8){0, 0, 0, 0, 0, 0, 0, 0};
      if (lg < 2) a = *(const bf16x8*)(zl + ((lr * 1536 + q * 32 + lg * 16) ^ ((lr & 7) << 4)));
      f32x4 c = {0, 0, 0, 0};
      c = __builtin_amdgcn_mfma_f32_16x16x32_bf16(a, w2r[qq], c, 0, 0, 0);
#pragma unroll
      for (int i = 0; i < 4; ++i) {
        unsigned int h = (unsigned int)f2bf(c[i]);
        if (qq & 1) upk[i][qq >> 1] |= (h << 16);
        else        upk[i][qq >> 1] = h;
      }
    }
    __syncthreads();   // all zl reads done; reuse zl as row-major u tile

    // u[row][n = lr*48 + wid*12 + qq] -> zl row-major (swizzled)
#pragma unroll
    for (int i = 0; i < 4; ++i) {
      int row = lg * 4 + i;
      int base = row * 1536 + lr * 96 + wid * 24;
      int swz = (row & 7) << 4;
#pragma unroll
      for (int p = 0; p < 3; ++p) {
        uint2 v; v.x = upk[i][p * 2]; v.y = upk[i][p * 2 + 1];
        *(uint2*)(zl + ((base + p * 8) ^ swz)) = v;
      }
    }
    __syncthreads();

    // coalesced copy: 24KB -> mx row-major
#pragma unroll
    for (int p = 0; p < 6; ++p) {
      int id = p * 256 + tid;              // 1536 x 16B chunks
      int row = id / 96, c16 = id - row * 96;
      f32x4 v = *(const f32x4*)(zl + ((row * 1536 + c16 * 16) ^ ((row & 7) << 4)));
      *(f32x4*)((unsigned char*)mx + (m0 + row) * 1536 + c16 * 16) = v;
    }
  } else if (bid < 3328) {
    int e = (bid - 1024) * 256 + threadIdx.x;   // 589824
    Gwb[e] = f2bf(gw[e]);
  } else {
    // pack Ow into MFMA B-fragment order: 16B chunk r = (nt*24+ks)*64+lane;
    // lane = lr + 16*lg holds Ow[nt*16+lr][ks*32 + lg*8 .. +7]
    int r = (bid - 3328) * 256 + threadIdx.x;   // 73728
    int lane = r & 63;
    int ks = (r >> 6) % 24;
    int nt = r / (24 * 64);
    int n = nt * 16 + (lane & 15);
    int k = ks * 32 + (lane >> 4) * 8;
    bf16x8 pack;
#pragma unroll
    for (int j = 0; j < 8; ++j) pack[j] = (short)f2bf(ow[(size_t)n * HD + k + j]);
    *(bf16x8*)(Opk + (size_t)r * 8) = pack;
  }
}

// ---------------- gate_mix: h = sigmoid(x@Gw^T+gb) * mixed ----------------
// BM=128, BN=192, grid 512 (2 blocks/CU), 4 waves, wave tile 64x96,
// depth-2 gload_lds staging. Epilogue: mx tile LDS-staged (coalesced) then
// read from LDS -- replaces 96 scattered 2B global reads per thread.
__global__ __launch_bounds__(256, 2)
void gate_mix_kernel(const unsigned short* __restrict__ xb,
                     const unsigned short* __restrict__ Gwb,
                     const float* __restrict__ gate_b,
                     const unsigned short* __restrict__ mx,
                     unsigned short* __restrict__ hb) {
  __shared__ __align__(16) unsigned char lds[81920];   // A 2x16K | B 2x24K
  const int tid = threadIdx.x, lane = tid & 63;
  const int wid = tid >> 6, wm = wid >> 1, wn = wid & 1;
  const int lr = lane & 15, lg = lane >> 4;

  const int b = blockIdx.x;                      // 512 blocks, 64 per XCD
  const int work = (b & 7) * 64 + (b >> 3);
  const int panel = work >> 2, nwin = work & 3;
  const size_t m0 = (size_t)panel * 128;
  const int n0 = nwin * 192;

  const int r0 = tid >> 3;
  const int sw = ((tid & 7) << 4) ^ ((r0 & 7) << 4);
  const int o0 = (0 * 32 + r0) * 1536 + sw;
  const int o1 = (1 * 32 + r0) * 1536 + sw;
  const int o2 = (2 * 32 + r0) * 1536 + sw;
  const int o3 = (3 * 32 + r0) * 1536 + sw;
  const int o4 = (4 * 32 + r0) * 1536 + sw;
  const int o5 = (5 * 32 + r0) * 1536 + sw;
  const unsigned char* aS = (const unsigned char*)xb + m0 * 1536;
  const unsigned char* bS = (const unsigned char*)Gwb + (size_t)n0 * 1536;

#define STAGE_A(KT, BUF) { const unsigned char* sp = aS + (KT) * 128; \
    gload_lds16(sp + o0, lds + (BUF) * 16384 + tid * 16); \
    gload_lds16(sp + o1, lds + (BUF) * 16384 + 4096 + tid * 16); \
    gload_lds16(sp + o2, lds + (BUF) * 16384 + 8192 + tid * 16); \
    gload_lds16(sp + o3, lds + (BUF) * 16384 + 12288 + tid * 16); }
#define STAGE_B(KT, BUF) { const unsigned char* sp = bS + (KT) * 128; \
    gload_lds16(sp + o0, lds + 32768 + (BUF) * 24576 + tid * 16); \
    gload_lds16(sp + o1, lds + 32768 + (BUF) * 24576 + 4096 + tid * 16); \
    gload_lds16(sp + o2, lds + 32768 + (BUF) * 24576 + 8192 + tid * 16); \
    gload_lds16(sp + o3, lds + 32768 + (BUF) * 24576 + 12288 + tid * 16); \
    gload_lds16(sp + o4, lds + 32768 + (BUF) * 24576 + 16384 + tid * 16); \
    gload_lds16(sp + o5, lds + 32768 + (BUF) * 24576 + 20480 + tid * 16); }

  const int sx0 = (lg * 16) ^ ((lr & 7) << 4);
  const int sx1 = sx0 ^ 64;
  const unsigned char* baA0 = lds + (wm * 64 + lr) * 128 + sx0;
  const unsigned char* baA1 = lds + (wm * 64 + lr) * 128 + sx1;
  const unsigned char* baB0 = lds + 32768 + (wn * 96 + lr) * 128 + sx0;
  const unsigned char* baB1 = lds + 32768 + (wn * 96 + lr) * 128 + sx1;

  f32x4 acc[4][6];
#pragma unroll
  for (int mt = 0; mt < 4; ++mt)
#pragma unroll
    for (int nt = 0; nt < 6; ++nt) acc[mt][nt] = (f32x4){0, 0, 0, 0};

  bf16x8 aA[4], aB[4];
  bf16x8 bB0[6], bB1[6];

#define RD_AA(BUF) { _Pragma("unroll") for (int mt = 0; mt < 4; ++mt) \
      aA[mt] = *(const bf16x8*)(baA0 + (BUF) * 16384 + mt * 2048); }
#define RD_AB(BUF) { _Pragma("unroll") for (int mt = 0; mt < 4; ++mt) \
      aB[mt] = *(const bf16x8*)(baA1 + (BUF) * 16384 + mt * 2048); }
#define RD_B0(BUF) { _Pragma("unroll") for (int nt = 0; nt < 6; ++nt) \
      bB0[nt] = *(const bf16x8*)(baB0 + (BUF) * 24576 + nt * 2048); }
#define RD_B1(BUF) { _Pragma("unroll") for (int nt = 0; nt < 6; ++nt) \
      bB1[nt] = *(const bf16x8*)(baB1 + (BUF) * 24576 + nt * 2048); }
#define MM24(AR, BR) { __builtin_amdgcn_s_setprio(1); \
    _Pragma("unroll") for (int mt = 0; mt < 4; ++mt) \
    _Pragma("unroll") for (int nt = 0; nt < 6; ++nt) \
      acc[mt][nt] = __builtin_amdgcn_mfma_f32_16x16x32_bf16(AR[mt], BR[nt], acc[mt][nt], 0, 0, 0); \
    __builtin_amdgcn_s_setprio(0); }

#define KT_BODY(KT, BUF, STG, VN) { \
    RD_AB(BUF); RD_B1(BUF); \
    LGKM(10); MM24(aA, bB0); \
    LGKM(0); \
    BAR(); \
    if (STG) { STAGE_A((KT) + 2, BUF); STAGE_B((KT) + 2, BUF); } \
    VMC(VN); \
    BAR(); \
    RD_AA((BUF) ^ 1); RD_B0((BUF) ^ 1); \
    MM24(aB, bB1); }

  STAGE_A(0, 0); STAGE_B(0, 0); STAGE_A(1, 1); STAGE_B(1, 1);
  VMC(10);
  BAR();
  RD_AA(0); RD_B0(0);

#pragma unroll 1
  for (int kt = 0; kt < 10; kt += 2) {
    KT_BODY(kt, 0, 1, 10);
    KT_BODY(kt + 1, 1, 1, 10);
  }
  KT_BODY(10, 0, 0, 0);
  // tail: kt = 11, buf 1; stage mx tile under the last two MM24s
  RD_AB(1); RD_B1(1);
  LGKM(0);
  BAR();                     // all waves' LDS reads retired; lds reusable
  {
    const unsigned char* ms = (const unsigned char*)mx + m0 * 1536 + (size_t)n0 * 2;
#pragma unroll
    for (int p = 0; p < 12; ++p) {
      int id = p * 256 + tid;            // 3072 x 16B = 48KB (128 rows x 384B)
      int row = id / 24, c16 = id - row * 24;
      gload_lds16(ms + row * 1536 + c16 * 16, lds + id * 16);
    }
  }
  MM24(aA, bB0);
  MM24(aB, bB1);
  VMC(0);
  BAR();

  // epilogue: h = sigmoid(y + gb) * mixed   (mixed from LDS)
#pragma unroll
  for (int nt = 0; nt < 6; ++nt) {
    const int col = n0 + wn * 96 + nt * 16 + lr;
    const int cl = wn * 96 + nt * 16 + lr;
    const float gbv = gate_b[col];
#pragma unroll
    for (int mt = 0; mt < 4; ++mt) {
#pragma unroll
      for (int i = 0; i < 4; ++i) {
        int rl = wm * 64 + mt * 16 + lg * 4 + i;
        size_t row = m0 + rl;
        float g = acc[mt][nt][i] + gbv;
        float s = 1.0f / (1.0f + __expf(-g));
        float mval = bf2f(*(const unsigned short*)(lds + rl * 384 + cl * 2));
        hb[row * 768 + col] = f2bf(s * mval);
      }
    }
  }
#undef STAGE_A
#undef STAGE_B
#undef RD_AA
#undef RD_AB
#undef RD_B0
#undef RD_B1
#undef MM24
#undef KT_BODY
}

// ---------------- fused out+LN: out = LN(h@Ow^T + ob + x) ----------------
// Round-0 schedule + xb residual tile LDS-staged (coalesced, overlapped with
// the final MM48) instead of 96 scattered 2B global reads per thread.
__global__ __launch_bounds__(512, 2)
void out_ln_kernel(const unsigned short* __restrict__ hb,
                   const unsigned short* __restrict__ Opk,
                   const float* __restrict__ out_b,
                   const unsigned short* __restrict__ xb,
                   const float* __restrict__ gamma,
                   const float* __restrict__ beta,
                   float* __restrict__ out) {
  __shared__ __align__(16) unsigned char lds[16384];    // A dbuf 2x8KB
  __shared__ __align__(16) unsigned char xlds[98304];   // 64 x 1536B residual tile
  __shared__ float psum[64][8];
  __shared__ float psq[64][8];

  const int tid = threadIdx.x, lane = tid & 63, wid = tid >> 6;
  const int lr = lane & 15, lg = lane >> 4;
  const size_t m0 = (size_t)blockIdx.x * 64;

  const int srow = tid >> 3;                                 // 0..63
  const unsigned char* aSrc = (const unsigned char*)hb + (m0 + srow) * 1536
                              + (((tid & 7) << 4) ^ ((srow & 7) << 4));
#define STAGE_A(KT, BUF) gload_lds16(aSrc + (KT) * 128, lds + (BUF) * 8192 + tid * 16)

  const unsigned short* bBase = Opk + ((size_t)(wid * 6) * 24 * 64 + lane) * 8;
#define LOAD_B(KT, BR) { _Pragma("unroll") for (int nt = 0; nt < 6; ++nt) { \
      BR[nt * 2 + 0] = *(const bf16x8*)(bBase + nt * 12288 + ((KT) * 2 + 0) * 512); \
      BR[nt * 2 + 1] = *(const bf16x8*)(bBase + nt * 12288 + ((KT) * 2 + 1) * 512); } }

  const int sx0 = (lg * 16) ^ ((lr & 7) << 4);
  const unsigned char* baA0 = lds + lr * 128 + sx0;
  const unsigned char* baA1 = lds + lr * 128 + (sx0 ^ 64);
#define RD_A(BUF) { _Pragma("unroll") for (int mt = 0; mt < 4; ++mt) { \
      aF0[mt] = *(const bf16x8*)(baA0 + (BUF) * 8192 + mt * 2048); \
      aF1[mt] = *(const bf16x8*)(baA1 + (BUF) * 8192 + mt * 2048); } }

#define MM48(BR) { __builtin_amdgcn_s_setprio(1); \
    _Pragma("unroll") for (int mt = 0; mt < 4; ++mt) \
    _Pragma("unroll") for (int nt = 0; nt < 6; ++nt) { \
      acc[mt][nt] = __builtin_amdgcn_mfma_f32_16x16x32_bf16(aF0[mt], BR[nt * 2 + 0], acc[mt][nt], 0, 0, 0); \
      acc[mt][nt] = __builtin_amdgcn_mfma_f32_16x16x32_bf16(aF1[mt], BR[nt * 2 + 1], acc[mt][nt], 0, 0, 0); } \
    __builtin_amdgcn_s_setprio(0); }

  f32x4 acc[4][6];
#pragma unroll
  for (int mt = 0; mt < 4; ++mt)
#pragma unroll
    for (int nt = 0; nt < 6; ++nt) acc[mt][nt] = (f32x4){0, 0, 0, 0};

  bf16x8 aF0[4], aF1[4];
  bf16x8 bP[12], bQ[12];

#define KT_BODY(KT, BUF, BCUR, BNXT) { \
    STAGE_A((KT) + 1, (BUF) ^ 1); LOAD_B((KT) + 1, BNXT); \
    RD_A(BUF); \
    LGKM(0); \
    VMC(13); \
    MM48(BCUR); \
    VMC(12); BAR(); }

  STAGE_A(0, 0);
  LOAD_B(0, bP);
  VMC(12);
  BAR();

#pragma unroll 1
  for (int kt = 0; kt < 10; kt += 2) {
    KT_BODY(kt, 0, bP, bQ);
    KT_BODY(kt + 1, 1, bQ, bP);
  }
  KT_BODY(10, 0, bP, bQ);
  // stage xb residual tile (64 x 1536B): 12 coalesced 16B chunks per thread.
  // bQ's 12 reg-loads are the 12 oldest vmem ops; these 12 stages are newest.
  {
    const unsigned char* xs = (const unsigned char*)xb + m0 * 1536;
#pragma unroll
    for (int p = 0; p < 12; ++p) {
      int id = p * 512 + tid;            // 6144 x 16B = 96KB
      int row = id / 96, c16 = id - row * 96;
      gload_lds16(xs + row * 1536 + c16 * 16, xlds + id * 16);
    }
  }
  // final kt = 11, buf 1
  RD_A(1);
  LGKM(0);
  VMC(12);          // retire bQ loads; xb stages remain in flight under MM48
  MM48(bQ);
  VMC(0);
  BAR();

  // ---- epilogue: t = y + ob + residual(xlds); LayerNorm; fp32 store ----
#pragma unroll
  for (int nt = 0; nt < 6; ++nt) {
    const int col = wid * 96 + nt * 16 + lr;
    const float obv = out_b[col];
#pragma unroll
    for (int mt = 0; mt < 4; ++mt) {
#pragma unroll
      for (int i = 0; i < 4; ++i) {
        int rl = mt * 16 + lg * 4 + i;
        acc[mt][nt][i] += obv + bf2f(*(const unsigned short*)(xlds + rl * 1536 + col * 2));
      }
    }
  }
#pragma unroll
  for (int mt = 0; mt < 4; ++mt) {
#pragma unroll
    for (int i = 0; i < 4; ++i) {
      float s = 0.f, q = 0.f;
#pragma unroll
      for (int nt = 0; nt < 6; ++nt) { float v = acc[mt][nt][i]; s += v; q += v * v; }
#pragma unroll
      for (int off = 8; off >= 1; off >>= 1) {
        s += __shfl_xor(s, off);
        q += __shfl_xor(q, off);
      }
      if (lr == 0) {
        int rl = mt * 16 + lg * 4 + i;
        psum[rl][wid] = s; psq[rl][wid] = q;
      }
    }
  }
  __syncthreads();
#pragma unroll
  for (int mt = 0; mt < 4; ++mt) {
#pragma unroll
    for (int i = 0; i < 4; ++i) {
      int rl = mt * 16 + lg * 4 + i;
      float s = 0.f, q = 0.f;
#pragma unroll
      for (int w = 0; w < 8; ++w) { s += psum[rl][w]; q += psq[rl][w]; }
      float mu = s * (1.0f / 768.0f);
      float var = q * (1.0f / 768.0f) - mu * mu;
      var = var < 0.f ? 0.f : var;
      float rstd = rsqrtf(var + 1e-12f);
      size_t grow = m0 + rl;
#pragma unroll
      for (int nt = 0; nt < 6; ++nt) {
        int col = wid * 96 + nt * 16 + lr;
        out[grow * 768 + col] = (acc[mt][nt][i] - mu) * rstd * gamma[col] + beta[col];
      }
    }
  }
#undef STAGE_A
#undef LOAD_B
#undef RD_A
#undef MM48
#undef KT_BODY
}

// ---------------- launch ----------------
extern "C" void kernel_launch(void* const* d_in, const int* in_sizes, int n_in,
                              void* d_out, int out_size, void* d_ws, size_t ws_size,
                              hipStream_t stream) {
  const float* x   = (const float*)d_in[0];
  const float* w1  = (const float*)d_in[1];
  const float* w2  = (const float*)d_in[2];
  const float* gw  = (const float*)d_in[3];
  const float* gb  = (const float*)d_in[4];
  const float* ow  = (const float*)d_in[5];
  const float* ob  = (const float*)d_in[6];
  const float* gam = (const float*)d_in[7];
  const float* bet = (const float*)d_in[8];
  float* out = (float*)d_out;

  char* ws = (char*)d_ws;
  unsigned short* xb  = (unsigned short*)(ws);                   // 25,165,824 B
  unsigned short* hb  = (unsigned short*)(ws + 25165824);        // 25,165,824 B
  unsigned short* Gwb = (unsigned short*)(ws + 50331648);        // 1,179,648 B
  unsigned short* Opk = (unsigned short*)(ws + 51511296);        // 1,179,648 B
  // mixed (25,165,824 B bf16) lives in d_out: written by prep_monarch,
  // read by gate_mix, then overwritten by out_ln's final fp32 store.
  unsigned short* mx  = (unsigned short*)d_out;

  prep_monarch_all_kernel<<<3616, 256, 0, stream>>>(x, gw, ow, w1, w2, xb, Gwb, Opk, mx);
  gate_mix_kernel<<<512, 256, 0, stream>>>(xb, Gwb, gb, mx, hb);
  out_ln_kernel<<<256, 512, 0, stream>>>(hb, Opk, ob, xb, gam, bet, out);
}

// Round 4
// 97.812 us; speedup vs baseline: 1.5453x; 1.5453x over previous
//
#include <hip/hip_runtime.h>
#include <hip/hip_bf16.h>
#include <stdint.h>

#define HD 768

typedef __attribute__((ext_vector_type(8))) short bf16x8;
typedef __attribute__((ext_vector_type(4))) float f32x4;
typedef __attribute__((ext_vector_type(4))) unsigned short u16x4;

typedef __attribute__((address_space(3))) void lds_void_t;
typedef const __attribute__((address_space(1))) void gbl_void_t;

__device__ inline void gload_lds16(const void* g, void* l) {
  __builtin_amdgcn_global_load_lds((gbl_void_t*)g, (lds_void_t*)l, 16, 0, 0);
}

__device__ inline unsigned short f2bf(float f) {
  union { float f; unsigned int u; } v; v.f = f;
  return (unsigned short)((v.u + 0x7fffu + ((v.u >> 16) & 1u)) >> 16);
}
__device__ inline float bf2f(unsigned short u) {
  union { unsigned int uu; float f; } v; v.uu = ((unsigned int)u) << 16;
  return v.f;
}

#define BAR() asm volatile("s_barrier" ::: "memory")
#define LGKM(N) { asm volatile("s_waitcnt lgkmcnt(" #N ")" ::: "memory"); __builtin_amdgcn_sched_barrier(0); }
#define VMC(N) asm volatile("s_waitcnt vmcnt(" #N ")" ::: "memory")

// ---------------- prep: cvt x + Gw (bf16 row-major) + packed Ow + monarch frags ----------------
// bid ranges: [0,12288) cvt x; [12288,14592) Gwb; [14592,14880) Opk; [14880,14904) w1f; [14904,14916) w2f.
__global__ void prep_all_kernel(const float* __restrict__ x,
                                const float* __restrict__ gw, const float* __restrict__ ow,
                                const float* __restrict__ w1, const float* __restrict__ w2,
                                unsigned short* __restrict__ xb,
                                unsigned short* __restrict__ Gwb,
                                unsigned short* __restrict__ Opk,
                                unsigned short* __restrict__ w1f,
                                unsigned short* __restrict__ w2f) {
  int bid = blockIdx.x;
  if (bid < 12288) {
    int i = bid * 256 + threadIdx.x;          // 3,145,728 float4s
    float4 v = ((const float4*)x)[i];
    ushort4 o;
    o.x = f2bf(v.x); o.y = f2bf(v.y); o.z = f2bf(v.z); o.w = f2bf(v.w);
    ((ushort4*)xb)[i] = o;
  } else if (bid < 14592) {
    int e = (bid - 12288) * 256 + threadIdx.x;   // 589824
    Gwb[e] = f2bf(gw[e]);
  } else if (bid < 14880) {
    // pack Ow into MFMA B-fragment order: 16B chunk r = (nt*24+ks)*64+lane;
    // lane = lr + 16*lg holds Ow[nt*16+lr][ks*32 + lg*8 .. +7]
    int r = (bid - 14592) * 256 + threadIdx.x;   // 73728
    int lane = r & 63;
    int ks = (r >> 6) % 24;
    int nt = r / (24 * 64);
    int n = nt * 16 + (lane & 15);
    int k = ks * 32 + (lane >> 4) * 8;
    bf16x8 pack;
#pragma unroll
    for (int j = 0; j < 8; ++j) pack[j] = (short)f2bf(ow[(size_t)n * HD + k + j]);
    *(bf16x8*)(Opk + (size_t)r * 8) = pack;
  } else if (bid < 14904) {
    // w1 B-frags: fi = (k*3+nt)*2+ks; frag value B[q_local=nt*16+lr][kk=ks*32+lg*8+j]
    //   = w1[k][kk][q_local] for kk<48 else 0.  w1 flat: k*2304 + i*48 + j.
    int e = (bid - 14880) * 256 + threadIdx.x;   // 6144
    int lane = e & 63, fi = e >> 6;
    int ks = fi & 1, nt = (fi >> 1) % 3, k = fi / 6;
    int lrr = lane & 15, lgg = lane >> 4;
    int q = nt * 16 + lrr;
    bf16x8 pack;
#pragma unroll
    for (int j = 0; j < 8; ++j) {
      int kk = ks * 32 + lgg * 8 + j;
      float v = (kk < 48) ? w1[(k * 48 + kk) * 48 + q] : 0.0f;
      pack[j] = (short)f2bf(v);
    }
    *(bf16x8*)(w1f + (size_t)e * 8) = pack;
  } else {
    // w2 B-frags: one per q; B[k2=lr][kk=lg*8+j] = w2[q][kk][k2] for kk<16 else 0.
    // w2 flat: q*256 + k*16 + j2.
    int e = (bid - 14904) * 256 + threadIdx.x;   // 3072
    int lane = e & 63, q = e >> 6;
    int lrr = lane & 15, lgg = lane >> 4;
    bf16x8 pack;
#pragma unroll
    for (int j = 0; j < 8; ++j) {
      int kk = lgg * 8 + j;
      float v = (kk < 16) ? w2[(q * 16 + kk) * 16 + lrr] : 0.0f;
      pack[j] = (short)f2bf(v);
    }
    *(bf16x8*)(w2f + (size_t)e * 8) = pack;
  }
}

// ---------------- monarch: mixed = P B2 P B1 x  (structured, 1.6 GFLOP) ----------------
// 512 blocks x 256 thr (4 waves), 32 rows/block, 48KB LDS, 2 blocks/CU.
__global__ __launch_bounds__(256, 2)
void monarch_kernel(const unsigned short* __restrict__ xb,
                    const unsigned short* __restrict__ w1f,
                    const unsigned short* __restrict__ w2f,
                    unsigned short* __restrict__ mx) {
  __shared__ __align__(16) unsigned char zl[49152];   // 32 x 768 bf16
  const int tid = threadIdx.x, lane = tid & 63, wid = tid >> 6;
  const int lr = lane & 15, lg = lane >> 4;
  const size_t m0 = (size_t)blockIdx.x * 32;

  // ---- stage 1 ----
#pragma unroll
  for (int kb = 0; kb < 4; ++kb) {
    const int k = wid * 4 + kb;
    const unsigned short* wf = w1f + (size_t)(k * 6) * 512 + lane * 8;
    bf16x8 b00 = *(const bf16x8*)(wf + 0 * 512);
    bf16x8 b01 = *(const bf16x8*)(wf + 1 * 512);
    bf16x8 b10 = *(const bf16x8*)(wf + 2 * 512);
    bf16x8 b11 = *(const bf16x8*)(wf + 3 * 512);
    bf16x8 b20 = *(const bf16x8*)(wf + 4 * 512);
    bf16x8 b21 = *(const bf16x8*)(wf + 5 * 512);
#pragma unroll
    for (int mt = 0; mt < 2; ++mt) {
      const unsigned short* ar = xb + (m0 + mt * 16 + lr) * 768 + k * 48;
      bf16x8 a0 = *(const bf16x8*)(ar + lg * 8);            // kk 0..31, all real
      bf16x8 a1 = (bf16x8){0, 0, 0, 0, 0, 0, 0, 0};
      if (lg < 2) a1 = *(const bf16x8*)(ar + 32 + lg * 8);  // kk 32..47 real; kk>=48 zero
      f32x4 c0 = {0, 0, 0, 0}, c1 = {0, 0, 0, 0}, c2 = {0, 0, 0, 0};
      c0 = __builtin_amdgcn_mfma_f32_16x16x32_bf16(a0, b00, c0, 0, 0, 0);
      c0 = __builtin_amdgcn_mfma_f32_16x16x32_bf16(a1, b01, c0, 0, 0, 0);
      c1 = __builtin_amdgcn_mfma_f32_16x16x32_bf16(a0, b10, c1, 0, 0, 0);
      c1 = __builtin_amdgcn_mfma_f32_16x16x32_bf16(a1, b11, c1, 0, 0, 0);
      c2 = __builtin_amdgcn_mfma_f32_16x16x32_bf16(a0, b20, c2, 0, 0, 0);
      c2 = __builtin_amdgcn_mfma_f32_16x16x32_bf16(a1, b21, c2, 0, 0, 0);
      // z[row][q*16+k], byte = row*1536 + q*32 + k*2, swizzle ^((row&7)<<4)
#pragma unroll
      for (int i = 0; i < 4; ++i) {
        int row = mt * 16 + lg * 4 + i;
        int base = row * 1536 + k * 2;
        int swz = (row & 7) << 4;
        *(unsigned short*)(zl + ((base + (0 * 16 + lr) * 32) ^ swz)) = f2bf(c0[i]);
        *(unsigned short*)(zl + ((base + (1 * 16 + lr) * 32) ^ swz)) = f2bf(c1[i]);
        *(unsigned short*)(zl + ((base + (2 * 16 + lr) * 32) ^ swz)) = f2bf(c2[i]);
      }
    }
  }
  __syncthreads();

  // ---- stage 2: u in regs, packed bf16 pairs along q ----
  unsigned int upk[2][4][6];
#pragma unroll
  for (int qq = 0; qq < 12; ++qq) {
    const int q = wid * 12 + qq;
    bf16x8 bw = *(const bf16x8*)(w2f + (size_t)q * 512 + lane * 8);
#pragma unroll
    for (int mt = 0; mt < 2; ++mt) {
      int row = mt * 16 + lr;
      int off = (row * 1536 + (lg < 2 ? q * 32 + lg * 16 : 0)) ^ ((row & 7) << 4);
      bf16x8 a = *(const bf16x8*)(zl + off);
      if (lg >= 2) a = (bf16x8){0, 0, 0, 0, 0, 0, 0, 0};
      f32x4 c = {0, 0, 0, 0};
      c = __builtin_amdgcn_mfma_f32_16x16x32_bf16(a, bw, c, 0, 0, 0);
#pragma unroll
      for (int i = 0; i < 4; ++i) {
        unsigned int h = (unsigned int)f2bf(c[i]);
        if (qq & 1) upk[mt][i][qq >> 1] |= (h << 16);
        else        upk[mt][i][qq >> 1] = h;
      }
    }
  }
  __syncthreads();   // all zl reads done; reuse zl as row-major u tile

  // u[row][n = lr*48 + wid*12 + qq] -> zl row-major (swizzled), b64 writes
  const int wq0 = wid * 12;
#pragma unroll
  for (int mt = 0; mt < 2; ++mt) {
#pragma unroll
    for (int i = 0; i < 4; ++i) {
      int row = mt * 16 + lg * 4 + i;
      int base = row * 1536 + lr * 96 + wq0 * 2;
      int swz = (row & 7) << 4;
#pragma unroll
      for (int p = 0; p < 3; ++p) {
        uint2 v; v.x = upk[mt][i][p * 2]; v.y = upk[mt][i][p * 2 + 1];
        *(uint2*)(zl + ((base + p * 8) ^ swz)) = v;
      }
    }
  }
  __syncthreads();

  // coalesced copy: 48KB -> mx row-major
#pragma unroll
  for (int p = 0; p < 12; ++p) {
    int id = p * 256 + tid;              // 3072 x 16B chunks
    int row = id / 96, w16 = id % 96;
    int by = (row * 1536 + w16 * 16) ^ ((row & 7) << 4);
    f32x4 v = *(const f32x4*)(zl + by);
    *(f32x4*)((unsigned char*)mx + (m0 + row) * 1536 + w16 * 16) = v;
  }
}

// ---------------- gate_mix: h = sigmoid(x@Gw^T+gb) * mixed ----------------
// BM=128, BN=192, grid 512 (2 blocks/CU), 4 waves, wave tile 64x96,
// depth-2 gload_lds staging. Epilogue: mx tile LDS-staged (coalesced).
__global__ __launch_bounds__(256, 2)
void gate_mix_kernel(const unsigned short* __restrict__ xb,
                     const unsigned short* __restrict__ Gwb,
                     const float* __restrict__ gate_b,
                     const unsigned short* __restrict__ mx,
                     unsigned short* __restrict__ hb) {
  __shared__ __align__(16) unsigned char lds[81920];   // A 2x16K | B 2x24K
  const int tid = threadIdx.x, lane = tid & 63;
  const int wid = tid >> 6, wm = wid >> 1, wn = wid & 1;
  const int lr = lane & 15, lg = lane >> 4;

  const int b = blockIdx.x;                      // 512 blocks, 64 per XCD
  const int work = (b & 7) * 64 + (b >> 3);
  const int panel = work >> 2, nwin = work & 3;
  const size_t m0 = (size_t)panel * 128;
  const int n0 = nwin * 192;

  const int r0 = tid >> 3;
  const int sw = ((tid & 7) << 4) ^ ((r0 & 7) << 4);
  const int o0 = (0 * 32 + r0) * 1536 + sw;
  const int o1 = (1 * 32 + r0) * 1536 + sw;
  const int o2 = (2 * 32 + r0) * 1536 + sw;
  const int o3 = (3 * 32 + r0) * 1536 + sw;
  const int o4 = (4 * 32 + r0) * 1536 + sw;
  const int o5 = (5 * 32 + r0) * 1536 + sw;
  const unsigned char* aS = (const unsigned char*)xb + m0 * 1536;
  const unsigned char* bS = (const unsigned char*)Gwb + (size_t)n0 * 1536;

#define STAGE_A(KT, BUF) { const unsigned char* sp = aS + (KT) * 128; \
    gload_lds16(sp + o0, lds + (BUF) * 16384 + tid * 16); \
    gload_lds16(sp + o1, lds + (BUF) * 16384 + 4096 + tid * 16); \
    gload_lds16(sp + o2, lds + (BUF) * 16384 + 8192 + tid * 16); \
    gload_lds16(sp + o3, lds + (BUF) * 16384 + 12288 + tid * 16); }
#define STAGE_B(KT, BUF) { const unsigned char* sp = bS + (KT) * 128; \
    gload_lds16(sp + o0, lds + 32768 + (BUF) * 24576 + tid * 16); \
    gload_lds16(sp + o1, lds + 32768 + (BUF) * 24576 + 4096 + tid * 16); \
    gload_lds16(sp + o2, lds + 32768 + (BUF) * 24576 + 8192 + tid * 16); \
    gload_lds16(sp + o3, lds + 32768 + (BUF) * 24576 + 12288 + tid * 16); \
    gload_lds16(sp + o4, lds + 32768 + (BUF) * 24576 + 16384 + tid * 16); \
    gload_lds16(sp + o5, lds + 32768 + (BUF) * 24576 + 20480 + tid * 16); }

  const int sx0 = (lg * 16) ^ ((lr & 7) << 4);
  const int sx1 = sx0 ^ 64;
  const unsigned char* baA0 = lds + (wm * 64 + lr) * 128 + sx0;
  const unsigned char* baA1 = lds + (wm * 64 + lr) * 128 + sx1;
  const unsigned char* baB0 = lds + 32768 + (wn * 96 + lr) * 128 + sx0;
  const unsigned char* baB1 = lds + 32768 + (wn * 96 + lr) * 128 + sx1;

  f32x4 acc[4][6];
#pragma unroll
  for (int mt = 0; mt < 4; ++mt)
#pragma unroll
    for (int nt = 0; nt < 6; ++nt) acc[mt][nt] = (f32x4){0, 0, 0, 0};

  bf16x8 aA[4], aB[4];
  bf16x8 bB0[6], bB1[6];

#define RD_AA(BUF) { _Pragma("unroll") for (int mt = 0; mt < 4; ++mt) \
      aA[mt] = *(const bf16x8*)(baA0 + (BUF) * 16384 + mt * 2048); }
#define RD_AB(BUF) { _Pragma("unroll") for (int mt = 0; mt < 4; ++mt) \
      aB[mt] = *(const bf16x8*)(baA1 + (BUF) * 16384 + mt * 2048); }
#define RD_B0(BUF) { _Pragma("unroll") for (int nt = 0; nt < 6; ++nt) \
      bB0[nt] = *(const bf16x8*)(baB0 + (BUF) * 24576 + nt * 2048); }
#define RD_B1(BUF) { _Pragma("unroll") for (int nt = 0; nt < 6; ++nt) \
      bB1[nt] = *(const bf16x8*)(baB1 + (BUF) * 24576 + nt * 2048); }
#define MM24(AR, BR) { __builtin_amdgcn_s_setprio(1); \
    _Pragma("unroll") for (int mt = 0; mt < 4; ++mt) \
    _Pragma("unroll") for (int nt = 0; nt < 6; ++nt) \
      acc[mt][nt] = __builtin_amdgcn_mfma_f32_16x16x32_bf16(AR[mt], BR[nt], acc[mt][nt], 0, 0, 0); \
    __builtin_amdgcn_s_setprio(0); }

#define KT_BODY(KT, BUF, STG, VN) { \
    RD_AB(BUF); RD_B1(BUF); \
    LGKM(10); MM24(aA, bB0); \
    LGKM(0); \
    BAR(); \
    if (STG) { STAGE_A((KT) + 2, BUF); STAGE_B((KT) + 2, BUF); } \
    VMC(VN); \
    BAR(); \
    RD_AA((BUF) ^ 1); RD_B0((BUF) ^ 1); \
    MM24(aB, bB1); }

  STAGE_A(0, 0); STAGE_B(0, 0); STAGE_A(1, 1); STAGE_B(1, 1);
  VMC(10);
  BAR();
  RD_AA(0); RD_B0(0);

#pragma unroll 1
  for (int kt = 0; kt < 10; kt += 2) {
    KT_BODY(kt, 0, 1, 10);
    KT_BODY(kt + 1, 1, 1, 10);
  }
  KT_BODY(10, 0, 0, 0);
  // tail: kt = 11, buf 1; stage mx tile under the last two MM24s
  RD_AB(1); RD_B1(1);
  LGKM(0);
  BAR();                     // all waves' LDS reads retired; lds reusable
  {
    const unsigned char* ms = (const unsigned char*)mx + m0 * 1536 + (size_t)n0 * 2;
#pragma unroll
    for (int p = 0; p < 12; ++p) {
      int id = p * 256 + tid;            // 3072 x 16B = 48KB (128 rows x 384B)
      int row = id / 24, c16 = id - row * 24;
      gload_lds16(ms + row * 1536 + c16 * 16, lds + id * 16);
    }
  }
  MM24(aA, bB0);
  MM24(aB, bB1);
  VMC(0);
  BAR();

  // epilogue: h = sigmoid(y + gb) * mixed   (mixed from LDS)
#pragma unroll
  for (int nt = 0; nt < 6; ++nt) {
    const int col = n0 + wn * 96 + nt * 16 + lr;
    const int cl = wn * 96 + nt * 16 + lr;
    const float gbv = gate_b[col];
#pragma unroll
    for (int mt = 0; mt < 4; ++mt) {
#pragma unroll
      for (int i = 0; i < 4; ++i) {
        int rl = wm * 64 + mt * 16 + lg * 4 + i;
        size_t row = m0 + rl;
        float g = acc[mt][nt][i] + gbv;
        float s = 1.0f / (1.0f + __expf(-g));
        float mval = bf2f(*(const unsigned short*)(lds + rl * 384 + cl * 2));
        hb[row * 768 + col] = f2bf(s * mval);
      }
    }
  }
#undef STAGE_A
#undef STAGE_B
#undef RD_AA
#undef RD_AB
#undef RD_B0
#undef RD_B1
#undef MM24
#undef KT_BODY
}

// ---------------- fused out+LN: out = LN(h@Ow^T + ob + x) ----------------
// Round-0 schedule + xb residual tile LDS-staged (coalesced, overlapped with
// the final MM48) instead of 96 scattered 2B global reads per thread.
__global__ __launch_bounds__(512, 2)
void out_ln_kernel(const unsigned short* __restrict__ hb,
                   const unsigned short* __restrict__ Opk,
                   const float* __restrict__ out_b,
                   const unsigned short* __restrict__ xb,
                   const float* __restrict__ gamma,
                   const float* __restrict__ beta,
                   float* __restrict__ out) {
  __shared__ __align__(16) unsigned char lds[16384];    // A dbuf 2x8KB
  __shared__ __align__(16) unsigned char xlds[98304];   // 64 x 1536B residual tile
  __shared__ float psum[64][8];
  __shared__ float psq[64][8];

  const int tid = threadIdx.x, lane = tid & 63, wid = tid >> 6;
  const int lr = lane & 15, lg = lane >> 4;
  const size_t m0 = (size_t)blockIdx.x * 64;

  const int srow = tid >> 3;                                 // 0..63
  const unsigned char* aSrc = (const unsigned char*)hb + (m0 + srow) * 1536
                              + (((tid & 7) << 4) ^ ((srow & 7) << 4));
#define STAGE_A(KT, BUF) gload_lds16(aSrc + (KT) * 128, lds + (BUF) * 8192 + tid * 16)

  const unsigned short* bBase = Opk + ((size_t)(wid * 6) * 24 * 64 + lane) * 8;
#define LOAD_B(KT, BR) { _Pragma("unroll") for (int nt = 0; nt < 6; ++nt) { \
      BR[nt * 2 + 0] = *(const bf16x8*)(bBase + nt * 12288 + ((KT) * 2 + 0) * 512); \
      BR[nt * 2 + 1] = *(const bf16x8*)(bBase + nt * 12288 + ((KT) * 2 + 1) * 512); } }

  const int sx0 = (lg * 16) ^ ((lr & 7) << 4);
  const unsigned char* baA0 = lds + lr * 128 + sx0;
  const unsigned char* baA1 = lds + lr * 128 + (sx0 ^ 64);
#define RD_A(BUF) { _Pragma("unroll") for (int mt = 0; mt < 4; ++mt) { \
      aF0[mt] = *(const bf16x8*)(baA0 + (BUF) * 8192 + mt * 2048); \
      aF1[mt] = *(const bf16x8*)(baA1 + (BUF) * 8192 + mt * 2048); } }

#define MM48(BR) { __builtin_amdgcn_s_setprio(1); \
    _Pragma("unroll") for (int mt = 0; mt < 4; ++mt) \
    _Pragma("unroll") for (int nt = 0; nt < 6; ++nt) { \
      acc[mt][nt] = __builtin_amdgcn_mfma_f32_16x16x32_bf16(aF0[mt], BR[nt * 2 + 0], acc[mt][nt], 0, 0, 0); \
      acc[mt][nt] = __builtin_amdgcn_mfma_f32_16x16x32_bf16(aF1[mt], BR[nt * 2 + 1], acc[mt][nt], 0, 0, 0); } \
    __builtin_amdgcn_s_setprio(0); }

  f32x4 acc[4][6];
#pragma unroll
  for (int mt = 0; mt < 4; ++mt)
#pragma unroll
    for (int nt = 0; nt < 6; ++nt) acc[mt][nt] = (f32x4){0, 0, 0, 0};

  bf16x8 aF0[4], aF1[4];
  bf16x8 bP[12], bQ[12];

#define KT_BODY(KT, BUF, BCUR, BNXT) { \
    STAGE_A((KT) + 1, (BUF) ^ 1); LOAD_B((KT) + 1, BNXT); \
    RD_A(BUF); \
    LGKM(0); \
    VMC(13); \
    MM48(BCUR); \
    VMC(12); BAR(); }

  STAGE_A(0, 0);
  LOAD_B(0, bP);
  VMC(12);
  BAR();

#pragma unroll 1
  for (int kt = 0; kt < 10; kt += 2) {
    KT_BODY(kt, 0, bP, bQ);
    KT_BODY(kt + 1, 1, bQ, bP);
  }
  KT_BODY(10, 0, bP, bQ);
  // stage xb residual tile (64 x 1536B): 12 coalesced 16B chunks per thread.
  {
    const unsigned char* xs = (const unsigned char*)xb + m0 * 1536;
#pragma unroll
    for (int p = 0; p < 12; ++p) {
      int id = p * 512 + tid;            // 6144 x 16B = 96KB
      int row = id / 96, c16 = id - row * 96;
      gload_lds16(xs + row * 1536 + c16 * 16, xlds + id * 16);
    }
  }
  // final kt = 11, buf 1
  RD_A(1);
  LGKM(0);
  VMC(12);          // retire bQ loads; xb stages remain in flight under MM48
  MM48(bQ);
  VMC(0);
  BAR();

  // ---- epilogue: t = y + ob + residual(xlds); LayerNorm; fp32 store ----
#pragma unroll
  for (int nt = 0; nt < 6; ++nt) {
    const int col = wid * 96 + nt * 16 + lr;
    const float obv = out_b[col];
#pragma unroll
    for (int mt = 0; mt < 4; ++mt) {
#pragma unroll
      for (int i = 0; i < 4; ++i) {
        int rl = mt * 16 + lg * 4 + i;
        acc[mt][nt][i] += obv + bf2f(*(const unsigned short*)(xlds + rl * 1536 + col * 2));
      }
    }
  }
#pragma unroll
  for (int mt = 0; mt < 4; ++mt) {
#pragma unroll
    for (int i = 0; i < 4; ++i) {
      float s = 0.f, q = 0.f;
#pragma unroll
      for (int nt = 0; nt < 6; ++nt) { float v = acc[mt][nt][i]; s += v; q += v * v; }
#pragma unroll
      for (int off = 8; off >= 1; off >>= 1) {
        s += __shfl_xor(s, off);
        q += __shfl_xor(q, off);
      }
      if (lr == 0) {
        int rl = mt * 16 + lg * 4 + i;
        psum[rl][wid] = s; psq[rl][wid] = q;
      }
    }
  }
  __syncthreads();
#pragma unroll
  for (int mt = 0; mt < 4; ++mt) {
#pragma unroll
    for (int i = 0; i < 4; ++i) {
      int rl = mt * 16 + lg * 4 + i;
      float s = 0.f, q = 0.f;
#pragma unroll
      for (int w = 0; w < 8; ++w) { s += psum[rl][w]; q += psq[rl][w]; }
      float mu = s * (1.0f / 768.0f);
      float var = q * (1.0f / 768.0f) - mu * mu;
      var = var < 0.f ? 0.f : var;
      float rstd = rsqrtf(var + 1e-12f);
      size_t grow = m0 + rl;
#pragma unroll
      for (int nt = 0; nt < 6; ++nt) {
        int col = wid * 96 + nt * 16 + lr;
        out[grow * 768 + col] = (acc[mt][nt][i] - mu) * rstd * gamma[col] + beta[col];
      }
    }
  }
#undef STAGE_A
#undef LOAD_B
#undef RD_A
#undef MM48
#undef KT_BODY
}

// ---------------- launch ----------------
extern "C" void kernel_launch(void* const* d_in, const int* in_sizes, int n_in,
                              void* d_out, int out_size, void* d_ws, size_t ws_size,
                              hipStream_t stream) {
  const float* x   = (const float*)d_in[0];
  const float* w1  = (const float*)d_in[1];
  const float* w2  = (const float*)d_in[2];
  const float* gw  = (const float*)d_in[3];
  const float* gb  = (const float*)d_in[4];
  const float* ow  = (const float*)d_in[5];
  const float* ob  = (const float*)d_in[6];
  const float* gam = (const float*)d_in[7];
  const float* bet = (const float*)d_in[8];
  float* out = (float*)d_out;

  char* ws = (char*)d_ws;
  unsigned short* xb  = (unsigned short*)(ws);                   // 25,165,824 B
  unsigned short* hb  = (unsigned short*)(ws + 25165824);        // 25,165,824 B
  unsigned short* Gwb = (unsigned short*)(ws + 50331648);        // 1,179,648 B
  unsigned short* Opk = (unsigned short*)(ws + 51511296);        // 1,179,648 B
  unsigned short* w1f = (unsigned short*)(ws + 52690944);        //    98,304 B
  unsigned short* w2f = (unsigned short*)(ws + 52789248);        //    49,152 B
  // mixed (25,165,824 B bf16) lives in d_out: written by monarch,
  // read by gate_mix, then overwritten by out_ln's final fp32 store.
  unsigned short* mx  = (unsigned short*)d_out;

  prep_all_kernel<<<14916, 256, 0, stream>>>(x, gw, ow, w1, w2, xb, Gwb, Opk, w1f, w2f);
  monarch_kernel<<<512, 256, 0, stream>>>(xb, w1f, w2f, mx);
  gate_mix_kernel<<<512, 256, 0, stream>>>(xb, Gwb, gb, mx, hb);
  out_ln_kernel<<<256, 512, 0, stream>>>(hb, Opk, ob, xb, gam, bet, out);
}